// Round 5
// baseline (152.989 us; speedup 1.0000x reference)
//
#include <hip/hip_runtime.h>

// Problem constants (fixed by reference setup_inputs)
#define NB 32
#define NC 128
#define NH 63
#define NW 63
#define HW (NH*NW)     // 3969
#define OH 30
#define OW 30
#define SEGW 19        // columns per segment (8 tiles: x0=0..14 -> cols 0..18)
#define POSN (5*SEGW)  // 95 band positions per segment
#define KSTR 40        // bf16 row stride (32 ch + 8 pad): 80B, period-8 bank spread
#define CCH 32         // channels per chunk
#define NCHUNK (NC/CCH)
#define NSEG 4         // segments per strip (tiles 0-7, 8-15, 16-23, 24-29)
#define NBLK (NB*OH*NSEG)   // 3840

typedef __attribute__((ext_vector_type(8)))  __bf16 bf16x8;
typedef __attribute__((ext_vector_type(16))) float  f32x16;

__global__ void init_tops(float* tops) {
    if (threadIdx.x < NB) tops[threadIdx.x] = 0.0f;
}

__global__ __launch_bounds__(512, 8) void tile_mfma_kernel(const float* __restrict__ f,
                                                           float* __restrict__ tops) {
    // XCD-chunked swizzle (bijective: 3840 = 8*480): adjacent strips share 3/5 rows.
    const int swz   = (blockIdx.x & 7) * (NBLK / 8) + (blockIdx.x >> 3);
    const int strip = swz >> 2;          // (b, oi)
    const int g     = swz & 3;           // segment
    const int b     = strip / OH;
    const int oi    = strip % OH;
    const int y0    = oi * 2;
    const int xlo   = 16 * g;
    const int t     = threadIdx.x;
    const int w     = t >> 6;            // wave id = local tile id
    const int q     = t & 31;            // MFMA col (and A row p)
    const int h     = (t >> 5) & 1;      // k-half
    const int tile  = 8 * g + w;
    const bool tvalid = (tile < OH);

    __shared__ __align__(16) unsigned short band_hi[POSN * KSTR];
    __shared__ __align__(16) unsigned short band_lo[POSN * KSTR];
    __shared__ float nrm2[POSN];
    __shared__ float smax[8];

    if (t < POSN) nrm2[t] = 0.0f;

    // A-fragment row position for this lane (local band coords), clamped for p>=25
    const int posq = (q < 25) ? (q / 5) * SEGW + (q % 5) + 2 * w : 0;

    f32x16 acc = {};
    const float* fb = f + (size_t)b * NC * HW + (size_t)y0 * NW;

    for (int ch = 0; ch < NCHUNK; ++ch) {
        __syncthreads();   // prev chunk consumed (also orders nrm2 zeroing)
        // ---- stage 95 pos x 16 channel-pairs: coalesced global, packed hi/lo bf16 ----
        for (int u = t; u < POSN * 16; u += 512) {
            const int kp  = u / POSN;
            const int pos = u - kp * POSN;
            const int r   = pos / SEGW;
            const int xx  = pos - r * SEGW;
            const int x   = xlo + xx;
            if (x < NW) {
                const int c = ch * CCH + 2 * kp;
                const float x0f = fb[(size_t)c * HW + r * NW + x];
                const float x1f = fb[(size_t)(c + 1) * HW + r * NW + x];
                const unsigned b0 = __float_as_uint(x0f);
                const unsigned b1 = __float_as_uint(x1f);
                // hi = truncate-to-bf16 (top 16 bits); pack two hi's in one u32
                const unsigned hip = __builtin_amdgcn_perm(b1, b0, 0x07060302u);
                const float h0 = __uint_as_float(b0 & 0xffff0000u);
                const float h1 = __uint_as_float(b1 & 0xffff0000u);
                const float l0 = x0f - h0, l1 = x1f - h1;
                const unsigned lop = __builtin_amdgcn_perm(
                    __float_as_uint(l1), __float_as_uint(l0), 0x07060302u);
                ((unsigned*)band_hi)[pos * (KSTR / 2) + kp] = hip;
                ((unsigned*)band_lo)[pos * (KSTR / 2) + kp] = lop;
                atomicAdd(&nrm2[pos], x0f * x0f + x1f * x1f);  // exact fp32 norms
            }
        }
        __syncthreads();   // band + norms(chunk) ready
        // ---- Gram via MFMA: A-frag == B-frag for P*P^T ----
        if (tvalid) {
            #pragma unroll
            for (int ks = 0; ks < 2; ++ks) {
                const int off = posq * KSTR + ks * 16 + h * 8;   // 16B-aligned
                const bf16x8 ahi = *(const bf16x8*)&band_hi[off];
                const bf16x8 alo = *(const bf16x8*)&band_lo[off];
                acc = __builtin_amdgcn_mfma_f32_32x32x16_bf16(ahi, ahi, acc, 0, 0, 0);
                acc = __builtin_amdgcn_mfma_f32_32x32x16_bf16(ahi, alo, acc, 0, 0, 0);
                acc = __builtin_amdgcn_mfma_f32_32x32x16_bf16(alo, ahi, acc, 0, 0, 0);
            }
        }
    }

    __syncthreads();                       // all nrm2 atomics done
    if (t < POSN) nrm2[t] = sqrtf(nrm2[t]);
    __syncthreads();

    // ---- epilogue, in-register: colsum over p (== 25*s[q] by symmetry) ----
    float v = -1e30f;
    if (tvalid) {
        const float nq = nrm2[posq];
        float colsum = 0.0f;
        #pragma unroll
        for (int r = 0; r < 16; ++r) {
            const int row = (r & 3) + 8 * (r >> 2) + 4 * h;   // C/D row map (m74/m101)
            if (row < 25) {
                const int posr = (row / 5) * SEGW + (row % 5) + 2 * w;
                const float npr = nrm2[posr];
                const float denom = fmaxf(npr * nq, 1e-6f);
                colsum += 1.0f - acc[r] / denom;
            }
        }
        colsum += __shfl_xor(colsum, 32);                     // join k-halves' rows
        if (q < 25) v = colsum * (1.0f / 25.0f);
    }
    #pragma unroll
    for (int off = 1; off <= 16; off <<= 1) v = fmaxf(v, __shfl_xor(v, off));
    if ((t & 63) == 0) smax[w] = v;
    __syncthreads();
    if (t == 0) {
        float m = smax[0];
        #pragma unroll
        for (int i = 1; i < 8; ++i) m = fmaxf(m, smax[i]);
        m = fmaxf(m, 0.0f);  // keep int-punned atomicMax valid
        atomicMax((int*)&tops[b], __float_as_int(m));
    }
}

__global__ void finalize(const float* __restrict__ tops,
                         const int* __restrict__ label,
                         float* __restrict__ out) {
    if (threadIdx.x == 0) {
        float fs = 0.0f, rs = 0.0f, fc = 0.0f, rc = 0.0f;
        for (int b = 0; b < NB; ++b) {
            const float tb = tops[b];
            const float lb = (float)label[b];
            fs += tb * lb;          fc += lb;
            rs += tb * (1.0f - lb); rc += (1.0f - lb);
        }
        const float loss = 1.0f - fs / fc + rs / rc;
        out[0] = fmaxf(loss, 0.0f);
    }
}

extern "C" void kernel_launch(void* const* d_in, const int* in_sizes, int n_in,
                              void* d_out, int out_size, void* d_ws, size_t ws_size,
                              hipStream_t stream) {
    const float* feature = (const float*)d_in[0];
    const int* label     = (const int*)d_in[1];
    float* out  = (float*)d_out;
    float* tops = (float*)d_ws;   // 32 floats of scratch

    init_tops<<<1, 64, 0, stream>>>(tops);
    tile_mfma_kernel<<<NBLK, 512, 0, stream>>>(feature, tops);
    finalize<<<1, 64, 0, stream>>>(tops, label, out);
}